// Round 12
// baseline (383.777 us; speedup 1.0000x reference)
//
#include <hip/hip_runtime.h>
#include <hip/hip_bf16.h>

#define NNODES 50000
#define NEDGES 300000
#define NGRAPH 2048
#define NFEAT  128
#define NHID   256
#define DOUT   32
#define NROWS  50048   // 64-aligned row allocation for GEMM over-read

typedef __bf16 bf16x8 __attribute__((ext_vector_type(8)));
typedef float  f32x4  __attribute__((ext_vector_type(4)));
typedef unsigned short ushort8v __attribute__((ext_vector_type(8)));
typedef __attribute__((address_space(1))) const void* gas_ptr;
typedef __attribute__((address_space(3))) void* las_ptr;

__device__ __forceinline__ float bf2f(unsigned short u) {
    return __uint_as_float(((unsigned)u) << 16);
}
__device__ __forceinline__ unsigned short f2bf(float f) {
    unsigned u = __float_as_uint(f);
    unsigned r = u + 0x7FFFu + ((u >> 16) & 1u);   // RNE
    return (unsigned short)(r >> 16);
}

// ---------- prep: cast x -> bf16, weights -> bf16 (layer weights pre-swizzled), zero cnt/fill ----
__global__ __launch_bounds__(256) void prep_k(const float* __restrict__ x, unsigned short* __restrict__ x16,
                                              const float* __restrict__ W1, const float* __restrict__ W2,
                                              const float* __restrict__ W3, const float* __restrict__ Wf1,
                                              const float* __restrict__ Wf2,
                                              unsigned short* __restrict__ Wt1, unsigned short* __restrict__ Wt2,
                                              unsigned short* __restrict__ Wt3, unsigned short* __restrict__ Wf1t,
                                              unsigned short* __restrict__ Wf2t,
                                              int* __restrict__ cnt, int* __restrict__ fill) {
    int idx = blockIdx.x * 256 + threadIdx.x;
    if (idx < 800000) {                       // x cast, 8 elems/thread
        int i = idx * 8;
        float4 a = *(const float4*)&x[i];
        float4 b = *(const float4*)&x[i + 4];
        ushort4 lo = { f2bf(a.x), f2bf(a.y), f2bf(a.z), f2bf(a.w) };
        ushort4 hi = { f2bf(b.x), f2bf(b.y), f2bf(b.z), f2bf(b.w) };
        *(ushort4*)&x16[i] = lo;
        *(ushort4*)&x16[i + 4] = hi;
        return;
    }
    int t = idx - 800000;
    if (t < 200704) {
        const float* W; unsigned short* Wt; int K, N, base; bool sw;
        if      (t <  32768) { W = W1;  Wt = Wt1;  K = 128; N = 256; base = 0;      sw = true; }
        else if (t <  98304) { W = W2;  Wt = Wt2;  K = 256; N = 256; base = 32768;  sw = true; }
        else if (t < 163840) { W = W3;  Wt = Wt3;  K = 256; N = 256; base = 98304;  sw = true; }
        else if (t < 196608) { W = Wf1; Wt = Wf1t; K = 256; N = 128; base = 163840; sw = false; }
        else                 { W = Wf2; Wt = Wf2t; K = 128; N = 32;  base = 196608; sw = false; }
        int i = t - base; int n = i / K, k = i - n * K;
        unsigned short v = f2bf(W[(size_t)k * N + n]);
        if (sw) Wt[(k >> 5) * 8192 + n * 32 + (k & 31)] = v;   // sliced layout (N=256)
        else    Wt[i] = v;                                      // row-major [n][K]
        return;
    }
    t -= 200704;
    if (t < NNODES) { cnt[t] = 0; fill[t] = 0; }
}

__global__ __launch_bounds__(256) void edge_hist_k(const int* __restrict__ dst, int* cnt, int E) {
    int e = blockIdx.x * 256 + threadIdx.x;
    if (e < E) atomicAdd(&cnt[dst[e]], 1);
}

// block-level scan + dinv (chunk = 1024 nodes)
__global__ __launch_bounds__(1024) void scan_block_k(const int* __restrict__ cnt, int* __restrict__ rowp,
                                                     int* __restrict__ part, float* __restrict__ dinv, int n) {
    __shared__ int s[1024];
    int tid = threadIdx.x;
    int i = blockIdx.x * 1024 + tid;
    int v = (i < n) ? cnt[i] : 0;
    if (i < n) dinv[i] = rsqrtf((float)(v + 1));   // +1 self-loop
    s[tid] = v;
    __syncthreads();
    for (int off = 1; off < 1024; off <<= 1) {
        int t = (tid >= off) ? s[tid - off] : 0;
        __syncthreads();
        s[tid] += t;
        __syncthreads();
    }
    if (i < n) rowp[i] = s[tid] - v;               // exclusive, pre-offset
    if (tid == 1023) part[blockIdx.x] = s[1023];
}

// scatter + rowp finalize (folds scan_add): each block LDS-scans the 49 partials
__global__ __launch_bounds__(256) void scatter_k(const int* __restrict__ src, const int* __restrict__ dst,
                                                 const int* __restrict__ rowp_pre, const int* __restrict__ part,
                                                 int* fill, const float* __restrict__ dinv,
                                                 int* __restrict__ col, float* __restrict__ nrm,
                                                 int* __restrict__ rowp_fin, int E, int n, int nb) {
    __shared__ int s[64];
    int tid = threadIdx.x;
    if (tid < 64) s[tid] = (tid < nb) ? part[tid] : 0;
    __syncthreads();
    for (int off = 1; off < 64; off <<= 1) {
        int t = 0;
        if (tid < 64 && tid >= off) t = s[tid - off];
        __syncthreads();
        if (tid < 64) s[tid] += t;
        __syncthreads();
    }
    int gid = blockIdx.x * 256 + tid;
    if (gid <= n) {
        if (gid < n) {
            int ch = gid >> 10;
            int base = (ch == 0) ? 0 : s[ch - 1];
            rowp_fin[gid] = rowp_pre[gid] + base;
        } else {
            rowp_fin[n] = s[nb - 1];
        }
    }
    if (gid < E) {
        int ss = src[gid], d = dst[gid];
        int ch = d >> 10;
        int base = (ch == 0) ? 0 : s[ch - 1];
        int p = rowp_pre[d] + base + atomicAdd(&fill[d], 1);
        col[p] = ss;
        nrm[p] = dinv[ss] * dinv[d];
    }
}

// ---------- persistent weight-stationary GEMM, tile-level double-buffered ----------
// Grid = G blocks. Full weight [256 x K] in LDS (staged once). Each block loops tiles
// t, t+G, t+2G...; while tile t runs its 64 MFMAs, tile t+G's 16 A-fragments stream
// into the alternate register set. flags: bit0 relu, bit1 bias.
template<int K>
__global__ __launch_bounds__(512, 2) void gemm_ws_k(const unsigned short* __restrict__ A,
                                                    const unsigned short* __restrict__ Bsw,
                                                    const float* __restrict__ bias,
                                                    unsigned short* __restrict__ C,
                                                    int M, int flags) {
    __shared__ unsigned short Bs[256 * K];     // K=256: 128 KB; K=128: 64 KB
    constexpr int NKT = K / 32;
    const int tid = threadIdx.x;
    const int lane = tid & 63;
    const int wave = tid >> 6;                 // 0..7
    const int m = lane & 15, q = lane >> 4;
    const int wr = (wave >> 2) * 32;           // 0 / 32
    const int wc = (wave & 3) * 64;            // 0 / 64 / 128 / 192
    const int G = gridDim.x;
    const int nt = NROWS / 64;                 // 782

    // stage full weight: linear copy (global is pre-swizzled)
    constexpr int passes = (256 * K / 8) / 512;
#pragma unroll
    for (int p = 0; p < passes; ++p) {
        const unsigned short* g = &Bsw[(p * 512 + tid) * 8];
        __builtin_amdgcn_global_load_lds((gas_ptr)g, (las_ptr)&Bs[(p * 512 + wave * 64) * 8], 16, 0, 0);
    }
    __syncthreads();   // the only barrier

    bf16x8 a0[NKT][2], a1[NKT][2];

    auto loadA = [&](int t, bf16x8 (&dst)[NKT][2]) {
        const unsigned short* Ab = &A[(size_t)(t * 64 + wr + m) * K + q * 8];
#pragma unroll
        for (int kt = 0; kt < NKT; ++kt)
#pragma unroll
            for (int i = 0; i < 2; ++i)
                dst[kt][i] = *(const bf16x8*)&Ab[(size_t)i * 16 * K + kt * 32];
    };
    auto compute = [&](int t, bf16x8 (&af)[NKT][2]) {
        f32x4 acc[2][4] = {};
#pragma unroll
        for (int kt = 0; kt < NKT; ++kt) {
            bf16x8 bfr[4];
#pragma unroll
            for (int j = 0; j < 4; ++j)
                bfr[j] = *(const bf16x8*)&Bs[kt * 8192 + (wc + j * 16 + m) * 32 + q * 8];
#pragma unroll
            for (int i = 0; i < 2; ++i)
#pragma unroll
                for (int j = 0; j < 4; ++j)
                    acc[i][j] = __builtin_amdgcn_mfma_f32_16x16x32_bf16(af[kt][i], bfr[j], acc[i][j], 0, 0, 0);
        }
        const int rowBase = t * 64;
#pragma unroll
        for (int i = 0; i < 2; ++i) {
#pragma unroll
            for (int j = 0; j < 4; ++j) {
                int c = wc + j * 16 + m;
                float bv = (flags & 2) ? bias[c] : 0.f;
#pragma unroll
                for (int r = 0; r < 4; ++r) {
                    int rr = rowBase + wr + i * 16 + q * 4 + r;
                    if (rr >= M) continue;
                    float v = acc[i][j][r] + bv;
                    if (flags & 1) v = fmaxf(v, 0.f);
                    C[(size_t)rr * 256 + c] = f2bf(v);
                }
            }
        }
    };

    int t = blockIdx.x;
    if (t >= nt) return;
    loadA(t, a0);
    for (; t < nt; t += 2 * G) {
        int t1 = t + G, t2 = t + 2 * G;
        if (t1 < nt) loadA(t1, a1);      // prefetch while a0 computes
        compute(t, a0);
        if (t1 < nt) {
            if (t2 < nt) loadA(t2, a0);  // prefetch while a1 computes
            compute(t1, a1);
        }
    }
}

// ---------- agg on 128-wide rows: z = A_hat @ x (quarter-wave: 4 edge streams x 16 lanes) ----------
__global__ __launch_bounds__(256) void agg128_k(const unsigned short* __restrict__ x,
                                                const int* __restrict__ rowp, const int* __restrict__ col,
                                                const float* __restrict__ nrm, const float* __restrict__ dinv,
                                                unsigned short* __restrict__ z, int n) {
    int wave = threadIdx.x >> 6;
    int lane = threadIdx.x & 63;
    int st = lane >> 4;          // edge stream 0..3
    int li = lane & 15;          // chunk within row (16 x 16B = 256B)
    int node = blockIdx.x * 4 + wave;
    if (node >= n) return;
    const ushort8v* tp = (const ushort8v*)x;
    float di = dinv[node], sw = di * di;
    float hsw = (st == 0) ? sw : 0.f;
    ushort8v u = tp[(size_t)node * 16 + li];
    float ac[8];
#pragma unroll
    for (int k = 0; k < 8; ++k) ac[k] = bf2f(u[k]) * hsw;
    int e0 = rowp[node], e1 = rowp[node + 1];
    for (int e = e0 + st; e < e1; e += 32) {
        int c[8]; float w[8];
#pragma unroll
        for (int j = 0; j < 8; ++j) {
            int ee = e + 4 * j;
            bool v = ee < e1;
            c[j] = v ? col[ee] : 0;
            w[j] = v ? nrm[ee] : 0.f;
        }
        ushort8v mm[8];
#pragma unroll
        for (int j = 0; j < 8; ++j) mm[j] = tp[(size_t)c[j] * 16 + li];
#pragma unroll
        for (int j = 0; j < 8; ++j)
#pragma unroll
            for (int k = 0; k < 8; ++k)
                ac[k] += bf2f(mm[j][k]) * w[j];
    }
#pragma unroll
    for (int k = 0; k < 8; ++k) ac[k] += __shfl_down(ac[k], 32, 64);
#pragma unroll
    for (int k = 0; k < 8; ++k) ac[k] += __shfl_down(ac[k], 16, 64);
    if (st == 0) {
        ushort8v o;
#pragma unroll
        for (int k = 0; k < 8; ++k) o[k] = f2bf(ac[k]);
        ((ushort8v*)(z + (size_t)node * 128))[li] = o;
    }
}

// ---------- agg on 256-wide rows: z = A_hat @ h (half-wave: 2 edge streams x 32 lanes) ----------
__global__ __launch_bounds__(256) void agg256_k(const unsigned short* __restrict__ t,
                                                const int* __restrict__ rowp, const int* __restrict__ col,
                                                const float* __restrict__ nrm, const float* __restrict__ dinv,
                                                unsigned short* __restrict__ z, int n) {
    int wave = threadIdx.x >> 6;
    int lane = threadIdx.x & 63;
    int half = lane >> 5;
    int li   = lane & 31;
    int node = blockIdx.x * 4 + wave;
    if (node >= n) return;
    const ushort8v* tp = (const ushort8v*)t;
    float di = dinv[node], sw = di * di;
    float hsw = half ? 0.f : sw;
    ushort8v u = tp[(size_t)node * 32 + li];
    float ac[8];
#pragma unroll
    for (int k = 0; k < 8; ++k) ac[k] = bf2f(u[k]) * hsw;
    int e0 = rowp[node], e1 = rowp[node + 1];
    for (int e = e0 + half; e < e1; e += 16) {
        int c[8]; float w[8];
#pragma unroll
        for (int j = 0; j < 8; ++j) {
            int ee = e + 2 * j;
            bool v = ee < e1;
            c[j] = v ? col[ee] : 0;
            w[j] = v ? nrm[ee] : 0.f;
        }
        ushort8v mm[8];
#pragma unroll
        for (int j = 0; j < 8; ++j) mm[j] = tp[(size_t)c[j] * 32 + li];
#pragma unroll
        for (int j = 0; j < 8; ++j)
#pragma unroll
            for (int k = 0; k < 8; ++k)
                ac[k] += bf2f(mm[j][k]) * w[j];
    }
#pragma unroll
    for (int k = 0; k < 8; ++k) ac[k] += __shfl_down(ac[k], 32, 64);
    if (half == 0) {
        ushort8v o;
#pragma unroll
        for (int k = 0; k < 8; ++k) o[k] = f2bf(ac[k]);
        ((ushort8v*)(z + (size_t)node * NHID))[li] = o;
    }
}

// ---------- pooling: one block per graph (bounds via binary search) ----------
__global__ __launch_bounds__(256) void pool_k(const unsigned short* __restrict__ h,
                                              const int* __restrict__ batch,
                                              unsigned short* __restrict__ hg, int n) {
    __shared__ float red[4][256];
    int g = blockIdx.x;
    int wave = threadIdx.x >> 6, lane = threadIdx.x & 63;
    int lo = 0, hi = n;
    while (lo < hi) { int mid = (lo + hi) >> 1; if (batch[mid] < g) lo = mid + 1; else hi = mid; }
    int s = lo;
    hi = n;
    while (lo < hi) { int mid = (lo + hi) >> 1; if (batch[mid] < g + 1) lo = mid + 1; else hi = mid; }
    int e = lo;
    const ushort4* hp = (const ushort4*)h;
    float4 acc = make_float4(0.f, 0.f, 0.f, 0.f);
    for (int i = s + wave; i < e; i += 4) {
        ushort4 v = hp[(size_t)i * 64 + lane];
        acc.x += bf2f(v.x); acc.y += bf2f(v.y); acc.z += bf2f(v.z); acc.w += bf2f(v.w);
    }
    *(float4*)&red[wave][lane * 4] = acc;
    __syncthreads();
    if (wave == 0) {
        float inv = 1.f / fmaxf((float)(e - s), 1.f);
        float v0 = red[0][lane*4+0] + red[1][lane*4+0] + red[2][lane*4+0] + red[3][lane*4+0];
        float v1 = red[0][lane*4+1] + red[1][lane*4+1] + red[2][lane*4+1] + red[3][lane*4+1];
        float v2 = red[0][lane*4+2] + red[1][lane*4+2] + red[2][lane*4+2] + red[3][lane*4+2];
        float v3 = red[0][lane*4+3] + red[1][lane*4+3] + red[2][lane*4+3] + red[3][lane*4+3];
        ushort4 o = { f2bf(v0 * inv), f2bf(v1 * inv), f2bf(v2 * inv), f2bf(v3 * inv) };
        ((ushort4*)(hg + (size_t)g * NHID))[lane] = o;
    }
}

// ---------- MLP head, fused: out = relu(HG@Wf1t^T + bf1) @ Wf2t^T + bf2 ----------
__global__ __launch_bounds__(256) void mlp_head_k(const unsigned short* __restrict__ HG,
                                                  const unsigned short* __restrict__ Wf1t,  // [128][256]
                                                  const unsigned short* __restrict__ Wf2t,  // [32][128]
                                                  const float* __restrict__ bf1, const float* __restrict__ bf2,
                                                  float* __restrict__ out) {
    __shared__ unsigned short As1[128 * 32];   // 8 KB
    __shared__ unsigned short Bs1[128 * 32];   // 8 KB
    __shared__ unsigned short R[128 * 128];    // 32 KB
    __shared__ unsigned short Bs2[32 * 128];   // 8 KB
    const int tid = threadIdx.x;
    const int lane = tid & 63, wave = tid >> 6;
    const int m = lane & 15, q = lane >> 4;
    const int rowBase = blockIdx.x * 128;
    const int wr = (wave >> 1) * 64;
    const int wc = (wave & 1) * 64;

#pragma unroll
    for (int c2 = 0; c2 < 2; ++c2) {
        const unsigned short* g = &Wf2t[(c2 * 256 + tid) * 8];
        __builtin_amdgcn_global_load_lds((gas_ptr)g, (las_ptr)&Bs2[(c2 * 256 + wave * 64) * 8], 16, 0, 0);
    }

    f32x4 acc[4][4] = {};
    for (int kt = 0; kt < 256; kt += 32) {
#pragma unroll
        for (int c2 = 0; c2 < 2; ++c2) {
            int u = c2 * 256 + tid;
            int row = u >> 2, kp = u & 3;
            const unsigned short* ga = &HG[(size_t)(rowBase + row) * 256 + kt + kp * 8];
            const unsigned short* gb = &Wf1t[(size_t)row * 256 + kt + kp * 8];
            __builtin_amdgcn_global_load_lds((gas_ptr)ga, (las_ptr)&As1[(c2 * 256 + wave * 64) * 8], 16, 0, 0);
            __builtin_amdgcn_global_load_lds((gas_ptr)gb, (las_ptr)&Bs1[(c2 * 256 + wave * 64) * 8], 16, 0, 0);
        }
        __syncthreads();
        bf16x8 af[4], bfr[4];
#pragma unroll
        for (int i = 0; i < 4; ++i) af[i] = *(const bf16x8*)&As1[(wr + i * 16 + m) * 32 + q * 8];
#pragma unroll
        for (int j = 0; j < 4; ++j) bfr[j] = *(const bf16x8*)&Bs1[(wc + j * 16 + m) * 32 + q * 8];
#pragma unroll
        for (int i = 0; i < 4; ++i)
#pragma unroll
            for (int j = 0; j < 4; ++j)
                acc[i][j] = __builtin_amdgcn_mfma_f32_16x16x32_bf16(af[i], bfr[j], acc[i][j], 0, 0, 0);
        __syncthreads();
    }
#pragma unroll
    for (int i = 0; i < 4; ++i)
#pragma unroll
        for (int j = 0; j < 4; ++j) {
            int c = wc + j * 16 + m;
            float bv = bf1[c];
#pragma unroll
            for (int r = 0; r < 4; ++r) {
                int rr = wr + i * 16 + q * 4 + r;
                R[rr * 128 + c] = f2bf(fmaxf(acc[i][j][r] + bv, 0.f));
            }
        }
    __syncthreads();

    const int wr2 = wave * 32;
    f32x4 acc2[2][2] = {};
#pragma unroll
    for (int s2 = 0; s2 < 4; ++s2) {
        bf16x8 af2[2], bf22[2];
#pragma unroll
        for (int i = 0; i < 2; ++i) af2[i] = *(const bf16x8*)&R[(wr2 + i * 16 + m) * 128 + s2 * 32 + q * 8];
#pragma unroll
        for (int ct = 0; ct < 2; ++ct) bf22[ct] = *(const bf16x8*)&Bs2[(ct * 16 + m) * 128 + s2 * 32 + q * 8];
#pragma unroll
        for (int i = 0; i < 2; ++i)
#pragma unroll
            for (int ct = 0; ct < 2; ++ct)
                acc2[i][ct] = __builtin_amdgcn_mfma_f32_16x16x32_bf16(af2[i], bf22[ct], acc2[i][ct], 0, 0, 0);
    }
#pragma unroll
    for (int i = 0; i < 2; ++i)
#pragma unroll
        for (int ct = 0; ct < 2; ++ct) {
            int c = ct * 16 + m;
            float bv = bf2[c];
#pragma unroll
            for (int r = 0; r < 4; ++r) {
                int rr = rowBase + wr2 + i * 16 + q * 4 + r;
                out[(size_t)rr * 32 + c] = acc2[i][ct][r] + bv;
            }
        }
}

extern "C" void kernel_launch(void* const* d_in, const int* in_sizes, int n_in,
                              void* d_out, int out_size, void* d_ws, size_t ws_size,
                              hipStream_t stream) {
    const float* x    = (const float*)d_in[0];
    const int*   ei   = (const int*)d_in[1];
    const int*   batch= (const int*)d_in[2];
    const float* W1   = (const float*)d_in[3];
    const float* b1   = (const float*)d_in[4];
    const float* W2   = (const float*)d_in[5];
    const float* b2   = (const float*)d_in[6];
    const float* W3   = (const float*)d_in[7];
    const float* b3   = (const float*)d_in[8];
    const float* Wf1  = (const float*)d_in[9];
    const float* bf1  = (const float*)d_in[10];
    const float* Wf2  = (const float*)d_in[11];
    const float* bf2  = (const float*)d_in[12];
    float* out = (float*)d_out;

    const int* e_src = ei;
    const int* e_dst = ei + NEDGES;

    char* ws = (char*)d_ws;
    size_t off = 0;
    auto alloc = [&](size_t bytes) -> void* {
        void* p = (void*)(ws + off);
        off += (bytes + 255) & ~(size_t)255;
        return p;
    };
    unsigned short* X16 = (unsigned short*)alloc((size_t)NROWS * NFEAT * 2);
    unsigned short* Za  = (unsigned short*)alloc((size_t)NROWS * NFEAT * 2);   // aggregated input
    unsigned short* Ha  = (unsigned short*)alloc((size_t)NROWS * NHID * 2);    // layer outputs
    unsigned short* Zb  = (unsigned short*)alloc((size_t)NROWS * NHID * 2);    // aggregated hidden
    unsigned short* Wt1 = (unsigned short*)alloc((size_t)NHID * NFEAT * 2);    // swizzled [4][256][32]
    unsigned short* Wt2 = (unsigned short*)alloc((size_t)NHID * NHID * 2);     // swizzled [8][256][32]
    unsigned short* Wt3 = (unsigned short*)alloc((size_t)NHID * NHID * 2);     // swizzled [8][256][32]
    unsigned short* Wf1t= (unsigned short*)alloc((size_t)NFEAT * NHID * 2);
    unsigned short* Wf2t= (unsigned short*)alloc((size_t)DOUT * NFEAT * 2);
    unsigned short* HG  = (unsigned short*)alloc((size_t)NGRAPH * NHID * 2);
    float* dinv = (float*)alloc((size_t)NNODES * 4);
    int*   cnt  = (int*)alloc((size_t)NNODES * 4);
    int*   fill = (int*)alloc((size_t)NNODES * 4);
    int*   rowp = (int*)alloc((size_t)(NNODES + 1) * 4);   // pre-offset
    int*   rowf = (int*)alloc((size_t)(NNODES + 1) * 4);   // finalized
    int*   col  = (int*)alloc((size_t)NEDGES * 4);
    float* nrm  = (float*)alloc((size_t)NEDGES * 4);
    int*   part = (int*)alloc((size_t)64 * 4);
    (void)alloc(131072);   // tail pad

    const int nb = (NNODES + 1023) / 1024;   // 49

    // ---- prep: casts + zero cnt/fill ----
    hipLaunchKernelGGL(prep_k, dim3((1050704 + 255) / 256), dim3(256), 0, stream,
                       x, X16, W1, W2, W3, Wf1, Wf2, Wt1, Wt2, Wt3, Wf1t, Wf2t, cnt, fill);
    // ---- CSR + norm ----
    hipLaunchKernelGGL(edge_hist_k, dim3((NEDGES + 255) / 256), dim3(256), 0, stream, e_dst, cnt, NEDGES);
    hipLaunchKernelGGL(scan_block_k, dim3(nb), dim3(1024), 0, stream, cnt, rowp, part, dinv, NNODES);
    hipLaunchKernelGGL(scatter_k, dim3((NEDGES + 255) / 256), dim3(256), 0, stream,
                       e_src, e_dst, rowp, part, fill, dinv, col, nrm, rowf, NEDGES, NNODES, nb);

    const int nagg = (NNODES + 3) / 4;      // 12500
    // ---- layer 1: Za = A_hat X ; Ha = relu(Za @ W1 + b1) ----
    hipLaunchKernelGGL(agg128_k, dim3(nagg), dim3(256), 0, stream,
                       X16, rowf, col, nrm, dinv, Za, NNODES);
    hipLaunchKernelGGL((gemm_ws_k<128>), dim3(512), dim3(512), 0, stream,
                       Za, Wt1, b1, Ha, NNODES, 3);
    // ---- layer 2 ----
    hipLaunchKernelGGL(agg256_k, dim3(nagg), dim3(256), 0, stream,
                       Ha, rowf, col, nrm, dinv, Zb, NNODES);
    hipLaunchKernelGGL((gemm_ws_k<256>), dim3(256), dim3(512), 0, stream,
                       Zb, Wt2, b2, Ha, NNODES, 3);
    // ---- layer 3 ----
    hipLaunchKernelGGL(agg256_k, dim3(nagg), dim3(256), 0, stream,
                       Ha, rowf, col, nrm, dinv, Zb, NNODES);
    hipLaunchKernelGGL((gemm_ws_k<256>), dim3(256), dim3(512), 0, stream,
                       Zb, Wt3, b3, Ha, NNODES, 3);

    // ---- pool (one block/graph) ----
    hipLaunchKernelGGL(pool_k, dim3(NGRAPH), dim3(256), 0, stream, Ha, batch, HG, NNODES);

    // ---- MLP head (fused) ----
    hipLaunchKernelGGL(mlp_head_k, dim3(NGRAPH / 128), dim3(256), 0, stream,
                       HG, Wf1t, Wf2t, bf1, bf2, out);
}

// Round 13
// 320.241 us; speedup vs baseline: 1.1984x; 1.1984x over previous
//
#include <hip/hip_runtime.h>
#include <hip/hip_bf16.h>

#define NNODES 50000
#define NEDGES 300000
#define NGRAPH 2048
#define NFEAT  128
#define NHID   256
#define DOUT   32
#define NROWS  50048   // 64-aligned row allocation for GEMM over-read

typedef __bf16 bf16x8 __attribute__((ext_vector_type(8)));
typedef float  f32x4  __attribute__((ext_vector_type(4)));
typedef unsigned short ushort8v __attribute__((ext_vector_type(8)));
typedef __attribute__((address_space(1))) const void* gas_ptr;
typedef __attribute__((address_space(3))) void* las_ptr;

__device__ __forceinline__ float bf2f(unsigned short u) {
    return __uint_as_float(((unsigned)u) << 16);
}
__device__ __forceinline__ unsigned short f2bf(float f) {
    unsigned u = __float_as_uint(f);
    unsigned r = u + 0x7FFFu + ((u >> 16) & 1u);   // RNE
    return (unsigned short)(r >> 16);
}

// ---------- prep: cast x -> bf16, weights -> bf16 (layer weights pre-swizzled), zero cnt/fill ----
__global__ __launch_bounds__(256) void prep_k(const float* __restrict__ x, unsigned short* __restrict__ x16,
                                              const float* __restrict__ W1, const float* __restrict__ W2,
                                              const float* __restrict__ W3, const float* __restrict__ Wf1,
                                              const float* __restrict__ Wf2,
                                              unsigned short* __restrict__ Wt1, unsigned short* __restrict__ Wt2,
                                              unsigned short* __restrict__ Wt3, unsigned short* __restrict__ Wf1t,
                                              unsigned short* __restrict__ Wf2t,
                                              int* __restrict__ cnt, int* __restrict__ fill) {
    int idx = blockIdx.x * 256 + threadIdx.x;
    if (idx < 800000) {                       // x cast, 8 elems/thread
        int i = idx * 8;
        float4 a = *(const float4*)&x[i];
        float4 b = *(const float4*)&x[i + 4];
        ushort4 lo = { f2bf(a.x), f2bf(a.y), f2bf(a.z), f2bf(a.w) };
        ushort4 hi = { f2bf(b.x), f2bf(b.y), f2bf(b.z), f2bf(b.w) };
        *(ushort4*)&x16[i] = lo;
        *(ushort4*)&x16[i + 4] = hi;
        return;
    }
    int t = idx - 800000;
    if (t < 200704) {
        const float* W; unsigned short* Wt; int K, N, base; bool sw;
        if      (t <  32768) { W = W1;  Wt = Wt1;  K = 128; N = 256; base = 0;      sw = true; }
        else if (t <  98304) { W = W2;  Wt = Wt2;  K = 256; N = 256; base = 32768;  sw = true; }
        else if (t < 163840) { W = W3;  Wt = Wt3;  K = 256; N = 256; base = 98304;  sw = true; }
        else if (t < 196608) { W = Wf1; Wt = Wf1t; K = 256; N = 128; base = 163840; sw = false; }
        else                 { W = Wf2; Wt = Wf2t; K = 128; N = 32;  base = 196608; sw = false; }
        int i = t - base; int n = i / K, k = i - n * K;
        unsigned short v = f2bf(W[(size_t)k * N + n]);
        if (sw) Wt[(k >> 5) * 8192 + n * 32 + (k & 31)] = v;   // sliced layout (N=256)
        else    Wt[i] = v;                                      // row-major [n][K]
        return;
    }
    t -= 200704;
    if (t < NNODES) { cnt[t] = 0; fill[t] = 0; }
}

__global__ __launch_bounds__(256) void edge_hist_k(const int* __restrict__ dst, int* cnt, int E) {
    int e = blockIdx.x * 256 + threadIdx.x;
    if (e < E) atomicAdd(&cnt[dst[e]], 1);
}

// block-level scan + dinv (chunk = 1024 nodes)
__global__ __launch_bounds__(1024) void scan_block_k(const int* __restrict__ cnt, int* __restrict__ rowp,
                                                     int* __restrict__ part, float* __restrict__ dinv, int n) {
    __shared__ int s[1024];
    int tid = threadIdx.x;
    int i = blockIdx.x * 1024 + tid;
    int v = (i < n) ? cnt[i] : 0;
    if (i < n) dinv[i] = rsqrtf((float)(v + 1));   // +1 self-loop
    s[tid] = v;
    __syncthreads();
    for (int off = 1; off < 1024; off <<= 1) {
        int t = (tid >= off) ? s[tid - off] : 0;
        __syncthreads();
        s[tid] += t;
        __syncthreads();
    }
    if (i < n) rowp[i] = s[tid] - v;               // exclusive, pre-offset
    if (tid == 1023) part[blockIdx.x] = s[1023];
}

// scatter + rowp finalize (folds scan_add): each block LDS-scans the 49 partials
__global__ __launch_bounds__(256) void scatter_k(const int* __restrict__ src, const int* __restrict__ dst,
                                                 const int* __restrict__ rowp_pre, const int* __restrict__ part,
                                                 int* fill, const float* __restrict__ dinv,
                                                 int* __restrict__ col, float* __restrict__ nrm,
                                                 int* __restrict__ rowp_fin, int E, int n, int nb) {
    __shared__ int s[64];
    int tid = threadIdx.x;
    if (tid < 64) s[tid] = (tid < nb) ? part[tid] : 0;
    __syncthreads();
    for (int off = 1; off < 64; off <<= 1) {
        int t = 0;
        if (tid < 64 && tid >= off) t = s[tid - off];
        __syncthreads();
        if (tid < 64) s[tid] += t;
        __syncthreads();
    }
    int gid = blockIdx.x * 256 + tid;
    if (gid <= n) {
        if (gid < n) {
            int ch = gid >> 10;
            int base = (ch == 0) ? 0 : s[ch - 1];
            rowp_fin[gid] = rowp_pre[gid] + base;
        } else {
            rowp_fin[n] = s[nb - 1];
        }
    }
    if (gid < E) {
        int ss = src[gid], d = dst[gid];
        int ch = d >> 10;
        int base = (ch == 0) ? 0 : s[ch - 1];
        int p = rowp_pre[d] + base + atomicAdd(&fill[d], 1);
        col[p] = ss;
        nrm[p] = dinv[ss] * dinv[d];
    }
}

// ---------- weight-stationary MFMA GEMM, LDS-repacked coalesced epilogue ----------
// One 64-row tile per block. Full weight [256 x K] staged to LDS (linear, pre-swizzled),
// barrier-free K-loop (A global->VGPR, B from LDS). Epilogue: acc -> LDS (padded 264
// stride, weights dead by then) -> ushort8 coalesced stores. flags: bit0 relu, bit1 bias.
template<int K>
__global__ __launch_bounds__(512, 2) void gemm_ws_k(const unsigned short* __restrict__ A,
                                                    const unsigned short* __restrict__ Bsw,
                                                    const float* __restrict__ bias,
                                                    unsigned short* __restrict__ C,
                                                    int M, int flags) {
    __shared__ unsigned short Bs[256 * K];     // K=256: 128 KB; K=128: 64 KB; reused for repack
    const int tid = threadIdx.x;
    const int lane = tid & 63;
    const int wave = tid >> 6;                 // 0..7
    const int m = lane & 15, q = lane >> 4;
    const int wr = (wave >> 2) * 32;           // 0 / 32
    const int wc = (wave & 3) * 64;            // 0 / 64 / 128 / 192
    const int rowBase = blockIdx.x * 64;

    // stage full weight: linear copy (global is pre-swizzled)
    constexpr int passes = (256 * K / 8) / 512;
#pragma unroll
    for (int p = 0; p < passes; ++p) {
        const unsigned short* g = &Bsw[(p * 512 + tid) * 8];
        __builtin_amdgcn_global_load_lds((gas_ptr)g, (las_ptr)&Bs[(p * 512 + wave * 64) * 8], 16, 0, 0);
    }
    __syncthreads();

    f32x4 acc[2][4] = {};
#pragma unroll
    for (int kt = 0; kt < K; kt += 32) {
        bf16x8 af[2];
#pragma unroll
        for (int i = 0; i < 2; ++i)
            af[i] = *(const bf16x8*)&A[(size_t)(rowBase + wr + i * 16 + m) * K + kt + q * 8];
        bf16x8 bfr[4];
#pragma unroll
        for (int j = 0; j < 4; ++j)
            bfr[j] = *(const bf16x8*)&Bs[(kt >> 5) * 8192 + (wc + j * 16 + m) * 32 + q * 8];
#pragma unroll
        for (int i = 0; i < 2; ++i)
#pragma unroll
            for (int j = 0; j < 4; ++j)
                acc[i][j] = __builtin_amdgcn_mfma_f32_16x16x32_bf16(af[i], bfr[j], acc[i][j], 0, 0, 0);
    }

    // ---- epilogue: repack via LDS (weights dead), then coalesced ushort8 stores ----
    __syncthreads();   // all waves done reading Bs
    unsigned short* tile = Bs;     // [64][264] padded (33.8 KB <= 64 KB)
#pragma unroll
    for (int i = 0; i < 2; ++i) {
#pragma unroll
        for (int j = 0; j < 4; ++j) {
            int c = wc + j * 16 + m;
            float bv = (flags & 2) ? bias[c] : 0.f;
#pragma unroll
            for (int r = 0; r < 4; ++r) {
                float v = acc[i][j][r] + bv;
                if (flags & 1) v = fmaxf(v, 0.f);
                tile[(wr + i * 16 + q * 4 + r) * 264 + c] = f2bf(v);
            }
        }
    }
    __syncthreads();
    // 64 rows x 256 cols = 2048 chunks of 8 ushorts; 4 chunks/thread, coalesced
#pragma unroll
    for (int u0 = 0; u0 < 4; ++u0) {
        int u = u0 * 512 + tid;
        int row = u >> 5, cc = (u & 31) * 8;
        int rr = rowBase + row;
        if (rr < M)
            *(ushort8v*)&C[(size_t)rr * 256 + cc] = *(const ushort8v*)&tile[row * 264 + cc];
    }
}

// ---------- agg on 128-wide rows: z = A_hat @ x (quarter-wave: 4 edge streams x 16 lanes) ----------
__global__ __launch_bounds__(256) void agg128_k(const unsigned short* __restrict__ x,
                                                const int* __restrict__ rowp, const int* __restrict__ col,
                                                const float* __restrict__ nrm, const float* __restrict__ dinv,
                                                unsigned short* __restrict__ z, int n) {
    int wave = threadIdx.x >> 6;
    int lane = threadIdx.x & 63;
    int st = lane >> 4;          // edge stream 0..3
    int li = lane & 15;          // chunk within row (16 x 16B = 256B)
    int node = blockIdx.x * 4 + wave;
    if (node >= n) return;
    const ushort8v* tp = (const ushort8v*)x;
    float di = dinv[node], sw = di * di;
    float hsw = (st == 0) ? sw : 0.f;
    ushort8v u = tp[(size_t)node * 16 + li];
    float ac[8];
#pragma unroll
    for (int k = 0; k < 8; ++k) ac[k] = bf2f(u[k]) * hsw;
    int e0 = rowp[node], e1 = rowp[node + 1];
    for (int e = e0 + st; e < e1; e += 32) {
        int c[8]; float w[8];
#pragma unroll
        for (int j = 0; j < 8; ++j) {
            int ee = e + 4 * j;
            bool v = ee < e1;
            c[j] = v ? col[ee] : 0;
            w[j] = v ? nrm[ee] : 0.f;
        }
        ushort8v mm[8];
#pragma unroll
        for (int j = 0; j < 8; ++j) mm[j] = tp[(size_t)c[j] * 16 + li];
#pragma unroll
        for (int j = 0; j < 8; ++j)
#pragma unroll
            for (int k = 0; k < 8; ++k)
                ac[k] += bf2f(mm[j][k]) * w[j];
    }
#pragma unroll
    for (int k = 0; k < 8; ++k) ac[k] += __shfl_down(ac[k], 32, 64);
#pragma unroll
    for (int k = 0; k < 8; ++k) ac[k] += __shfl_down(ac[k], 16, 64);
    if (st == 0) {
        ushort8v o;
#pragma unroll
        for (int k = 0; k < 8; ++k) o[k] = f2bf(ac[k]);
        ((ushort8v*)(z + (size_t)node * 128))[li] = o;
    }
}

// ---------- agg on 256-wide rows: z = A_hat @ h (half-wave: 2 edge streams x 32 lanes) ----------
__global__ __launch_bounds__(256) void agg256_k(const unsigned short* __restrict__ t,
                                                const int* __restrict__ rowp, const int* __restrict__ col,
                                                const float* __restrict__ nrm, const float* __restrict__ dinv,
                                                unsigned short* __restrict__ z, int n) {
    int wave = threadIdx.x >> 6;
    int lane = threadIdx.x & 63;
    int half = lane >> 5;
    int li   = lane & 31;
    int node = blockIdx.x * 4 + wave;
    if (node >= n) return;
    const ushort8v* tp = (const ushort8v*)t;
    float di = dinv[node], sw = di * di;
    float hsw = half ? 0.f : sw;
    ushort8v u = tp[(size_t)node * 32 + li];
    float ac[8];
#pragma unroll
    for (int k = 0; k < 8; ++k) ac[k] = bf2f(u[k]) * hsw;
    int e0 = rowp[node], e1 = rowp[node + 1];
    for (int e = e0 + half; e < e1; e += 16) {
        int c[8]; float w[8];
#pragma unroll
        for (int j = 0; j < 8; ++j) {
            int ee = e + 2 * j;
            bool v = ee < e1;
            c[j] = v ? col[ee] : 0;
            w[j] = v ? nrm[ee] : 0.f;
        }
        ushort8v mm[8];
#pragma unroll
        for (int j = 0; j < 8; ++j) mm[j] = tp[(size_t)c[j] * 32 + li];
#pragma unroll
        for (int j = 0; j < 8; ++j)
#pragma unroll
            for (int k = 0; k < 8; ++k)
                ac[k] += bf2f(mm[j][k]) * w[j];
    }
#pragma unroll
    for (int k = 0; k < 8; ++k) ac[k] += __shfl_down(ac[k], 32, 64);
    if (half == 0) {
        ushort8v o;
#pragma unroll
        for (int k = 0; k < 8; ++k) o[k] = f2bf(ac[k]);
        ((ushort8v*)(z + (size_t)node * NHID))[li] = o;
    }
}

// ---------- pooling: one block per graph (bounds via binary search) ----------
__global__ __launch_bounds__(256) void pool_k(const unsigned short* __restrict__ h,
                                              const int* __restrict__ batch,
                                              unsigned short* __restrict__ hg, int n) {
    __shared__ float red[4][256];
    int g = blockIdx.x;
    int wave = threadIdx.x >> 6, lane = threadIdx.x & 63;
    int lo = 0, hi = n;
    while (lo < hi) { int mid = (lo + hi) >> 1; if (batch[mid] < g) lo = mid + 1; else hi = mid; }
    int s = lo;
    hi = n;
    while (lo < hi) { int mid = (lo + hi) >> 1; if (batch[mid] < g + 1) lo = mid + 1; else hi = mid; }
    int e = lo;
    const ushort4* hp = (const ushort4*)h;
    float4 acc = make_float4(0.f, 0.f, 0.f, 0.f);
    for (int i = s + wave; i < e; i += 4) {
        ushort4 v = hp[(size_t)i * 64 + lane];
        acc.x += bf2f(v.x); acc.y += bf2f(v.y); acc.z += bf2f(v.z); acc.w += bf2f(v.w);
    }
    *(float4*)&red[wave][lane * 4] = acc;
    __syncthreads();
    if (wave == 0) {
        float inv = 1.f / fmaxf((float)(e - s), 1.f);
        float v0 = red[0][lane*4+0] + red[1][lane*4+0] + red[2][lane*4+0] + red[3][lane*4+0];
        float v1 = red[0][lane*4+1] + red[1][lane*4+1] + red[2][lane*4+1] + red[3][lane*4+1];
        float v2 = red[0][lane*4+2] + red[1][lane*4+2] + red[2][lane*4+2] + red[3][lane*4+2];
        float v3 = red[0][lane*4+3] + red[1][lane*4+3] + red[2][lane*4+3] + red[3][lane*4+3];
        ushort4 o = { f2bf(v0 * inv), f2bf(v1 * inv), f2bf(v2 * inv), f2bf(v3 * inv) };
        ((ushort4*)(hg + (size_t)g * NHID))[lane] = o;
    }
}

// ---------- MLP head, fused: out = relu(HG@Wf1t^T + bf1) @ Wf2t^T + bf2 ----------
__global__ __launch_bounds__(256) void mlp_head_k(const unsigned short* __restrict__ HG,
                                                  const unsigned short* __restrict__ Wf1t,  // [128][256]
                                                  const unsigned short* __restrict__ Wf2t,  // [32][128]
                                                  const float* __restrict__ bf1, const float* __restrict__ bf2,
                                                  float* __restrict__ out) {
    __shared__ unsigned short As1[128 * 32];   // 8 KB
    __shared__ unsigned short Bs1[128 * 32];   // 8 KB
    __shared__ unsigned short R[128 * 128];    // 32 KB
    __shared__ unsigned short Bs2[32 * 128];   // 8 KB
    const int tid = threadIdx.x;
    const int lane = tid & 63, wave = tid >> 6;
    const int m = lane & 15, q = lane >> 4;
    const int rowBase = blockIdx.x * 128;
    const int wr = (wave >> 1) * 64;
    const int wc = (wave & 1) * 64;

#pragma unroll
    for (int c2 = 0; c2 < 2; ++c2) {
        const unsigned short* g = &Wf2t[(c2 * 256 + tid) * 8];
        __builtin_amdgcn_global_load_lds((gas_ptr)g, (las_ptr)&Bs2[(c2 * 256 + wave * 64) * 8], 16, 0, 0);
    }

    f32x4 acc[4][4] = {};
    for (int kt = 0; kt < 256; kt += 32) {
#pragma unroll
        for (int c2 = 0; c2 < 2; ++c2) {
            int u = c2 * 256 + tid;
            int row = u >> 2, kp = u & 3;
            const unsigned short* ga = &HG[(size_t)(rowBase + row) * 256 + kt + kp * 8];
            const unsigned short* gb = &Wf1t[(size_t)row * 256 + kt + kp * 8];
            __builtin_amdgcn_global_load_lds((gas_ptr)ga, (las_ptr)&As1[(c2 * 256 + wave * 64) * 8], 16, 0, 0);
            __builtin_amdgcn_global_load_lds((gas_ptr)gb, (las_ptr)&Bs1[(c2 * 256 + wave * 64) * 8], 16, 0, 0);
        }
        __syncthreads();
        bf16x8 af[4], bfr[4];
#pragma unroll
        for (int i = 0; i < 4; ++i) af[i] = *(const bf16x8*)&As1[(wr + i * 16 + m) * 32 + q * 8];
#pragma unroll
        for (int j = 0; j < 4; ++j) bfr[j] = *(const bf16x8*)&Bs1[(wc + j * 16 + m) * 32 + q * 8];
#pragma unroll
        for (int i = 0; i < 4; ++i)
#pragma unroll
            for (int j = 0; j < 4; ++j)
                acc[i][j] = __builtin_amdgcn_mfma_f32_16x16x32_bf16(af[i], bfr[j], acc[i][j], 0, 0, 0);
        __syncthreads();
    }
#pragma unroll
    for (int i = 0; i < 4; ++i)
#pragma unroll
        for (int j = 0; j < 4; ++j) {
            int c = wc + j * 16 + m;
            float bv = bf1[c];
#pragma unroll
            for (int r = 0; r < 4; ++r) {
                int rr = wr + i * 16 + q * 4 + r;
                R[rr * 128 + c] = f2bf(fmaxf(acc[i][j][r] + bv, 0.f));
            }
        }
    __syncthreads();

    const int wr2 = wave * 32;
    f32x4 acc2[2][2] = {};
#pragma unroll
    for (int s2 = 0; s2 < 4; ++s2) {
        bf16x8 af2[2], bf22[2];
#pragma unroll
        for (int i = 0; i < 2; ++i) af2[i] = *(const bf16x8*)&R[(wr2 + i * 16 + m) * 128 + s2 * 32 + q * 8];
#pragma unroll
        for (int ct = 0; ct < 2; ++ct) bf22[ct] = *(const bf16x8*)&Bs2[(ct * 16 + m) * 128 + s2 * 32 + q * 8];
#pragma unroll
        for (int i = 0; i < 2; ++i)
#pragma unroll
            for (int ct = 0; ct < 2; ++ct)
                acc2[i][ct] = __builtin_amdgcn_mfma_f32_16x16x32_bf16(af2[i], bf22[ct], acc2[i][ct], 0, 0, 0);
    }
#pragma unroll
    for (int i = 0; i < 2; ++i)
#pragma unroll
        for (int ct = 0; ct < 2; ++ct) {
            int c = ct * 16 + m;
            float bv = bf2[c];
#pragma unroll
            for (int r = 0; r < 4; ++r) {
                int rr = rowBase + wr2 + i * 16 + q * 4 + r;
                out[(size_t)rr * 32 + c] = acc2[i][ct][r] + bv;
            }
        }
}

extern "C" void kernel_launch(void* const* d_in, const int* in_sizes, int n_in,
                              void* d_out, int out_size, void* d_ws, size_t ws_size,
                              hipStream_t stream) {
    const float* x    = (const float*)d_in[0];
    const int*   ei   = (const int*)d_in[1];
    const int*   batch= (const int*)d_in[2];
    const float* W1   = (const float*)d_in[3];
    const float* b1   = (const float*)d_in[4];
    const float* W2   = (const float*)d_in[5];
    const float* b2   = (const float*)d_in[6];
    const float* W3   = (const float*)d_in[7];
    const float* b3   = (const float*)d_in[8];
    const float* Wf1  = (const float*)d_in[9];
    const float* bf1  = (const float*)d_in[10];
    const float* Wf2  = (const float*)d_in[11];
    const float* bf2  = (const float*)d_in[12];
    float* out = (float*)d_out;

    const int* e_src = ei;
    const int* e_dst = ei + NEDGES;

    char* ws = (char*)d_ws;
    size_t off = 0;
    auto alloc = [&](size_t bytes) -> void* {
        void* p = (void*)(ws + off);
        off += (bytes + 255) & ~(size_t)255;
        return p;
    };
    unsigned short* X16 = (unsigned short*)alloc((size_t)NROWS * NFEAT * 2);
    unsigned short* Za  = (unsigned short*)alloc((size_t)NROWS * NFEAT * 2);   // aggregated input
    unsigned short* Ha  = (unsigned short*)alloc((size_t)NROWS * NHID * 2);    // layer outputs
    unsigned short* Zb  = (unsigned short*)alloc((size_t)NROWS * NHID * 2);    // aggregated hidden
    unsigned short* Wt1 = (unsigned short*)alloc((size_t)NHID * NFEAT * 2);    // swizzled [4][256][32]
    unsigned short* Wt2 = (unsigned short*)alloc((size_t)NHID * NHID * 2);     // swizzled [8][256][32]
    unsigned short* Wt3 = (unsigned short*)alloc((size_t)NHID * NHID * 2);     // swizzled [8][256][32]
    unsigned short* Wf1t= (unsigned short*)alloc((size_t)NFEAT * NHID * 2);
    unsigned short* Wf2t= (unsigned short*)alloc((size_t)DOUT * NFEAT * 2);
    unsigned short* HG  = (unsigned short*)alloc((size_t)NGRAPH * NHID * 2);
    float* dinv = (float*)alloc((size_t)NNODES * 4);
    int*   cnt  = (int*)alloc((size_t)NNODES * 4);
    int*   fill = (int*)alloc((size_t)NNODES * 4);
    int*   rowp = (int*)alloc((size_t)(NNODES + 1) * 4);   // pre-offset
    int*   rowf = (int*)alloc((size_t)(NNODES + 1) * 4);   // finalized
    int*   col  = (int*)alloc((size_t)NEDGES * 4);
    float* nrm  = (float*)alloc((size_t)NEDGES * 4);
    int*   part = (int*)alloc((size_t)64 * 4);
    (void)alloc(131072);   // tail pad

    const int nb = (NNODES + 1023) / 1024;   // 49

    // ---- prep: casts + zero cnt/fill ----
    hipLaunchKernelGGL(prep_k, dim3((1050704 + 255) / 256), dim3(256), 0, stream,
                       x, X16, W1, W2, W3, Wf1, Wf2, Wt1, Wt2, Wt3, Wf1t, Wf2t, cnt, fill);
    // ---- CSR + norm ----
    hipLaunchKernelGGL(edge_hist_k, dim3((NEDGES + 255) / 256), dim3(256), 0, stream, e_dst, cnt, NEDGES);
    hipLaunchKernelGGL(scan_block_k, dim3(nb), dim3(1024), 0, stream, cnt, rowp, part, dinv, NNODES);
    hipLaunchKernelGGL(scatter_k, dim3((NEDGES + 255) / 256), dim3(256), 0, stream,
                       e_src, e_dst, rowp, part, fill, dinv, col, nrm, rowf, NEDGES, NNODES, nb);

    const int ngemm = NROWS / 64;           // 782
    const int nagg  = (NNODES + 3) / 4;     // 12500
    // ---- layer 1: Za = A_hat X ; Ha = relu(Za @ W1 + b1) ----
    hipLaunchKernelGGL(agg128_k, dim3(nagg), dim3(256), 0, stream,
                       X16, rowf, col, nrm, dinv, Za, NNODES);
    hipLaunchKernelGGL((gemm_ws_k<128>), dim3(ngemm), dim3(512), 0, stream,
                       Za, Wt1, b1, Ha, NNODES, 3);
    // ---- layer 2 ----
    hipLaunchKernelGGL(agg256_k, dim3(nagg), dim3(256), 0, stream,
                       Ha, rowf, col, nrm, dinv, Zb, NNODES);
    hipLaunchKernelGGL((gemm_ws_k<256>), dim3(ngemm), dim3(512), 0, stream,
                       Zb, Wt2, b2, Ha, NNODES, 3);
    // ---- layer 3 ----
    hipLaunchKernelGGL(agg256_k, dim3(nagg), dim3(256), 0, stream,
                       Ha, rowf, col, nrm, dinv, Zb, NNODES);
    hipLaunchKernelGGL((gemm_ws_k<256>), dim3(ngemm), dim3(512), 0, stream,
                       Zb, Wt3, b3, Ha, NNODES, 3);

    // ---- pool (one block/graph) ----
    hipLaunchKernelGGL(pool_k, dim3(NGRAPH), dim3(256), 0, stream, Ha, batch, HG, NNODES);

    // ---- MLP head (fused) ----
    hipLaunchKernelGGL(mlp_head_k, dim3(NGRAPH / 128), dim3(256), 0, stream,
                       HG, Wf1t, Wf2t, bf1, bf2, out);
}